// Round 17
// baseline (33.556 us; speedup 1.0000x reference)
//
#include <hip/hip_runtime.h>
#include <math.h>

#define NR 256   // rules
#define NF 128   // features

typedef short  s16x8  __attribute__((ext_vector_type(8)));   // 8 bf16 bit patterns
typedef __bf16 bf16x8 __attribute__((ext_vector_type(8)));
typedef float  f32x16 __attribute__((ext_vector_type(16)));  // MFMA 32x32 acc

__device__ __forceinline__ unsigned short f2bf(float x) {
    unsigned int u = __float_as_uint(x);
    unsigned int r = (u + 0x7FFFu + ((u >> 16) & 1u)) >> 16;  // RNE
    return (unsigned short)r;
}
__device__ __forceinline__ float bf2f(unsigned short b) {
    return __uint_as_float(((unsigned int)b) << 16);
}
__device__ __forceinline__ bf16x8 as_bf(s16x8 v) {
    return __builtin_bit_cast(bf16x8, v);
}
__device__ __forceinline__ f32x16 mfma_bf16(s16x8 a, s16x8 b, f32x16 acc) {
    return __builtin_amdgcn_mfma_f32_32x32x16_bf16(as_bf(a), as_bf(b), acc, 0, 0, 0);
}

// ---------------------------------------------------------------------------
// ONE-KERNEL fused (r17). Rationale: r11 probe showed identical main runs at
// 16us after prep (reads follow cross-XCD WRITES of ws -> dirty-line L3 path)
// but 7us after another main (reads follow READS -> clean L2-replicated).
// r14/r15/r16 falsified pipeline-depth / chip-traffic / per-block-bytes.
// Fix: no workspace at all. Each wave converts its rule tile's params
// f32->bf16 JIT from the READ-ONLY inputs (never written -> L2-warm across
// replays, no RAW). S drops to single-pass u_hi . d_hi: for this data
// S <= -20 always (128 terms >= (d-mu)^2/2), exp(S) is absorbed into -28.0f
// in f32, and conversion errors scale RELATIVE to the terms, so sign/regime
// is preserved. Q path kept BIT-IDENTICAL to r8 (w_hi.dh + w_hi.dl + w_lo.dh)
// -- it is the sole source of the measured 0.0039 absmax.
// Structure per block: 512 thr, 8 waves, 32 batch cols; wave = rule tile.
// Per ks: lane reads mu/sigma (32B each, f32, L2-warm) + w3 scalars, converts
// to A-frags (a0 = u2_hi|u1_hi, a2 = w_hi|w_lo), then 3 (ks<8) or 2 (ks>=8)
// MFMAs. 40 MFMA/wave total.
// C/D layout (HW-verified): col=lane&31, row=(reg&3)+8*(reg>>2)+4*(lane>>5)
// ---------------------------------------------------------------------------
__global__ __launch_bounds__(512) void fnn_one(
    const float* __restrict__ data,
    const float* __restrict__ mu, const float* __restrict__ sigma,
    const float* __restrict__ w3,
    float* __restrict__ out)
{
    __shared__ s16x8 sBH[16][64], sBL[16][64];   // 32 KB
    __shared__ float sCr[NR], sW0[NR];
    __shared__ float redD[8][32], redN[8][32];

    const int tid = threadIdx.x;
    const int b0  = blockIdx.x * 32;

    // ---- B build (r8 verbatim): thread (bks,bln) -> 4 LDS entries
    {
        const int bks = tid >> 6;        // 0..7
        const int bln = tid & 63;
        const float* p = data + (size_t)(b0 + (bln & 31)) * NF
                              + bks * 16 + (bln >> 5) * 8;
        const float4 v0 = *(const float4*)(p);
        const float4 v1 = *(const float4*)(p + 4);
        const float dv[8] = {v0.x, v0.y, v0.z, v0.w, v1.x, v1.y, v1.z, v1.w};
        s16x8 e_d, e_dl, e_d2, e_d2l;
        #pragma unroll
        for (int j = 0; j < 8; ++j) {
            const float d  = dv[j];
            const float d2 = d * d;
            const unsigned short dh  = f2bf(d);
            const unsigned short d2h = f2bf(d2);
            e_d  [j] = (short)dh;
            e_dl [j] = (short)f2bf(d  - bf2f(dh));
            e_d2 [j] = (short)d2h;
            e_d2l[j] = (short)f2bf(d2 - bf2f(d2h));
        }
        sBH[bks    ][bln] = e_d2;   // ks<8  : d^2 hi
        sBL[bks    ][bln] = e_d2l;  // ks<8  : d^2 lo
        sBH[bks + 8][bln] = e_d;    // ks>=8 : d hi
        sBL[bks + 8][bln] = e_dl;   // ks>=8 : d lo
    }

    // ---- Cr/W0 cooperative (also pre-warms L2 with mu/sigma, coalesced):
    // thread t -> rule r = t>>1, feature half seg = t&1 (64 consecutive f).
    {
        const int r   = tid >> 1;
        const int seg = tid & 1;
        const float* mrow = mu    + (size_t)r * NF + seg * 64;
        const float* srow = sigma + (size_t)r * NF + seg * 64;
        float cc = 0.f;
        #pragma unroll 4
        for (int q = 0; q < 64; q += 4) {
            const float4 s4 = *(const float4*)(srow + q);
            const float4 m4 = *(const float4*)(mrow + q);
            cc += (-0.5f / fmaxf(s4.x * s4.x, 1e-30f)) * m4.x * m4.x;
            cc += (-0.5f / fmaxf(s4.y * s4.y, 1e-30f)) * m4.y * m4.y;
            cc += (-0.5f / fmaxf(s4.z * s4.z, 1e-30f)) * m4.z * m4.z;
            cc += (-0.5f / fmaxf(s4.w * s4.w, 1e-30f)) * m4.w * m4.w;
        }
        cc += __shfl_xor(cc, 1);            // partner lane = other half
        if (seg == 0) sCr[r] = cc;
        if (tid < NR) sW0[tid] = w3[(size_t)tid * (NF + 1)];
    }
    __syncthreads();

    const int wv   = tid >> 6;     // wave id == rule tile
    const int lane = tid & 63;
    const int col  = lane & 31;
    const int half = lane >> 5;

    const int r  = wv * 32 + (lane & 31);   // this lane's rule row
    const int fh = half * 8;
    const float* mrow = mu    + (size_t)r * NF;
    const float* srow = sigma + (size_t)r * NF;
    const float* wrow = w3    + (size_t)r * (NF + 1) + 1;

    f32x16 accS, accQ;
    #pragma unroll
    for (int e = 0; e < 16; ++e) { accS[e] = 0.f; accQ[e] = 0.f; }

    #pragma unroll 1
    for (int ks = 0; ks < 16; ++ks) {
        const int f0 = (ks & 7) * 16 + fh;
        // f32 param reads: 32B/lane, L2-warm (read-only inputs, pre-warmed)
        const float4 m40 = *(const float4*)(mrow + f0);
        const float4 m41 = *(const float4*)(mrow + f0 + 4);
        const float4 s40 = *(const float4*)(srow + f0);
        const float4 s41 = *(const float4*)(srow + f0 + 4);
        const float mv[8] = {m40.x, m40.y, m40.z, m40.w, m41.x, m41.y, m41.z, m41.w};
        const float sv[8] = {s40.x, s40.y, s40.z, s40.w, s41.x, s41.y, s41.z, s41.w};

        s16x8 a0, a2;
        if (ks < 8) {
            #pragma unroll
            for (int j = 0; j < 8; ++j) {
                const float s  = sv[j];
                const float u2 = -0.5f / fmaxf(s * s, 1e-30f);
                a0[j] = (short)f2bf(u2);                    // u2_hi
                a2[j] = (short)f2bf(wrow[f0 + j]);          // w_hi
            }
        } else {
            #pragma unroll
            for (int j = 0; j < 8; ++j) {
                const float s  = sv[j];
                const float m  = mv[j];
                const float u2 = -0.5f / fmaxf(s * s, 1e-30f);
                a0[j] = (short)f2bf(-2.0f * u2 * m);        // u1_hi
                const float w  = wrow[f0 + j];
                const unsigned short wh = f2bf(w);
                a2[j] = (short)f2bf(w - bf2f(wh));          // w_lo
            }
        }

        const s16x8 bh = sBH[ks][lane];      // ks<8: d2h ; ks>=8: dh
        accS = mfma_bf16(a0, bh, accS);      // u_hi . {d2h|dh}
        if (ks < 8) {                         // uniform branch
            accQ = mfma_bf16(a2, sBH[ks + 8][lane], accQ);  // w_hi . dh
            accQ = mfma_bf16(a2, sBL[ks + 8][lane], accQ);  // w_hi . dl
        } else {
            accQ = mfma_bf16(a2, bh, accQ);                 // w_lo . dh
        }
    }

    float den_p = 0.f, num_p = 0.f;
    #pragma unroll
    for (int reg = 0; reg < 16; ++reg) {
        const int rloc = (reg & 3) + 8 * (reg >> 2) + 4 * half;
        const int rule = wv * 32 + rloc;
        const float S  = accS[reg] + sCr[rule];
        const float rv = __expf(fminf(S, 0.f)) - 28.0f;   // RULE_OFFSET (10^-18==-28)
        const float cq = accQ[reg] + sW0[rule];
        den_p += rv;
        num_p += rv * cq;
    }
    den_p += __shfl_xor(den_p, 32);
    num_p += __shfl_xor(num_p, 32);
    if (half == 0) { redD[wv][col] = den_p; redN[wv][col] = num_p; }
    __syncthreads();

    if (tid < 32) {
        float den = 0.f, num = 0.f;
        #pragma unroll
        for (int w = 0; w < 8; ++w) { den += redD[w][tid]; num += redN[w][tid]; }
        out[b0 + tid] = 1.0f / (1.0f + __expf(-(num / den)));
    }
}

// ---------------------------------------------------------------------------
// fallback (batch not divisible by 32): fused f32 (round-2, known-good).
// ---------------------------------------------------------------------------
#define TBF 8
__global__ __launch_bounds__(256) void fnn_fused(
    const float* __restrict__ data,
    const float* __restrict__ mu, const float* __restrict__ sigma,
    const float* __restrict__ w3,
    float* __restrict__ out)
{
    __shared__ float d_tile[TBF][NF];
    __shared__ float red[TBF][2][4];

    const int tid = threadIdx.x;
    const int b0  = blockIdx.x * TBF;
    {
        const float4* src = (const float4*)(data + (size_t)b0 * NF);
        ((float4*)(&d_tile[0][0]))[tid] = src[tid];
    }
    __syncthreads();

    const float* mu_r = mu    + (size_t)tid * NF;
    const float* sg_r = sigma + (size_t)tid * NF;
    const float* w_r  = w3    + (size_t)tid * (NF + 1);

    float S[TBF], Q[TBF];
    #pragma unroll
    for (int b = 0; b < TBF; ++b) { S[b] = 0.f; Q[b] = 0.f; }

    #pragma unroll 2
    for (int f = 0; f < NF; f += 4) {
        const float4 m4 = *(const float4*)(mu_r + f);
        const float4 s4 = *(const float4*)(sg_r + f);
        const float w0 = w_r[1 + f + 0], w1 = w_r[1 + f + 1];
        const float w2 = w_r[1 + f + 2], w3v = w_r[1 + f + 3];
        float4 c4;
        c4.x = -0.5f / fmaxf(s4.x * s4.x, 1e-30f);
        c4.y = -0.5f / fmaxf(s4.y * s4.y, 1e-30f);
        c4.z = -0.5f / fmaxf(s4.z * s4.z, 1e-30f);
        c4.w = -0.5f / fmaxf(s4.w * s4.w, 1e-30f);
        #pragma unroll
        for (int b = 0; b < TBF; ++b) {
            const float4 d4 = *(const float4*)(&d_tile[b][f]);
            float t;
            t = d4.x - m4.x; S[b] = fmaf(t * t, c4.x, S[b]); Q[b] = fmaf(d4.x, w0,  Q[b]);
            t = d4.y - m4.y; S[b] = fmaf(t * t, c4.y, S[b]); Q[b] = fmaf(d4.y, w1,  Q[b]);
            t = d4.z - m4.z; S[b] = fmaf(t * t, c4.z, S[b]); Q[b] = fmaf(d4.z, w2,  Q[b]);
            t = d4.w - m4.w; S[b] = fmaf(t * t, c4.w, S[b]); Q[b] = fmaf(d4.w, w3v, Q[b]);
        }
    }

    const float bias = w_r[0];
    #pragma unroll
    for (int b = 0; b < TBF; ++b) {
        float rule = __expf(S[b]) - 28.0f;
        float rc   = rule * (bias + Q[b]);
        #pragma unroll
        for (int off = 32; off > 0; off >>= 1) {
            rule += __shfl_down(rule, off);
            rc   += __shfl_down(rc,   off);
        }
        if ((tid & 63) == 0) {
            red[b][0][tid >> 6] = rule;
            red[b][1][tid >> 6] = rc;
        }
    }
    __syncthreads();
    if (tid < TBF) {
        const float den = red[tid][0][0] + red[tid][0][1] + red[tid][0][2] + red[tid][0][3];
        const float num = red[tid][1][0] + red[tid][1][1] + red[tid][1][2] + red[tid][1][3];
        out[b0 + tid] = 1.0f / (1.0f + __expf(-(num / den)));
    }
}

extern "C" void kernel_launch(void* const* d_in, const int* in_sizes, int n_in,
                              void* d_out, int out_size, void* d_ws, size_t ws_size,
                              hipStream_t stream) {
    const float* data  = (const float*)d_in[0];
    const float* mu    = (const float*)d_in[1];
    const float* sigma = (const float*)d_in[2];
    const float* w3    = (const float*)d_in[3];
    float* out = (float*)d_out;

    const int batch = in_sizes[0] / NF;   // 8192

    if ((batch % 32) == 0) {
        fnn_one<<<batch / 32, 512, 0, stream>>>(data, mu, sigma, w3, out);
    } else {
        fnn_fused<<<batch / TBF, 256, 0, stream>>>(data, mu, sigma, w3, out);
    }
}

// Round 18
// 26.906 us; speedup vs baseline: 1.2472x; 1.2472x over previous
//
#include <hip/hip_runtime.h>
#include <math.h>

#define NR 256   // rules
#define NF 128   // features

typedef short  s16x8  __attribute__((ext_vector_type(8)));   // 8 bf16 bit patterns
typedef __bf16 bf16x8 __attribute__((ext_vector_type(8)));
typedef float  f32x16 __attribute__((ext_vector_type(16)));  // MFMA 32x32 acc

__device__ __forceinline__ unsigned short f2bf(float x) {
    unsigned int u = __float_as_uint(x);
    unsigned int r = (u + 0x7FFFu + ((u >> 16) & 1u)) >> 16;  // RNE
    return (unsigned short)r;
}
__device__ __forceinline__ float bf2f(unsigned short b) {
    return __uint_as_float(((unsigned int)b) << 16);
}
__device__ __forceinline__ bf16x8 as_bf(s16x8 v) {
    return __builtin_bit_cast(bf16x8, v);
}
__device__ __forceinline__ f32x16 mfma_bf16(s16x8 a, s16x8 b, f32x16 acc) {
    return __builtin_amdgcn_mfma_f32_32x32x16_bf16(as_bf(a), as_bf(b), acc, 0, 0, 0);
}

// ---------------------------------------------------------------------------
// r18: cooperative-JIT single kernel.
//  - r17 validated the numerics (single-pass S, 3-pass Q; absmax 0.0039) but
//    died on uncoalesced per-lane param reads (512B lane stride, the r2 bug).
//  - Here the conversion is COOPERATIVE & COALESCED: per km step, thread t ->
//    rule r=t>>1, f-half fh=t&1 reads 32B of sigma/mu (+8 w3 scalars),
//    converts to {u2,u1,w_hi,w_lo} frags, ds_writes into a double-buffered
//    A-stage (64KB). Conversion of km+1 overlaps MFMA of km (one barrier/km).
//  - No workspace, no producer-kernel RAW, read-only inputs stay L2/L3-warm
//    across graph replays. 40 MFMA/wave, 5 per km per wave.
//  math per (r,b): S = u2_hi.d2_hi + u1_hi.d_hi (+Cr, clamped <=0);
//                  Q = w_hi.d_hi + w_hi.d_lo + w_lo.d_hi (+W0)
//  out = sigmoid( sum_r (exp(S)-28)*Q / sum_r (exp(S)-28) )
// C/D layout (HW-verified): col=lane&31, row=(reg&3)+8*(reg>>2)+4*(lane>>5)
// ---------------------------------------------------------------------------
__global__ __launch_bounds__(512) void fnn_coop(
    const float* __restrict__ data,
    const float* __restrict__ mu, const float* __restrict__ sigma,
    const float* __restrict__ w3,
    float* __restrict__ out)
{
    // A-stage: [buf][array: 0=u2,1=u1,2=wh,3=wl][tile][lane] -> 64 KB
    __shared__ s16x8 sA[2][4][8][64];
    // B: [array: 0=d2h,1=dh,2=dl][km][lane] -> 24 KB
    __shared__ s16x8 sB[3][8][64];
    __shared__ float sCr[NR], sW0[NR];
    __shared__ float redD[8][32], redN[8][32];

    const int tid = threadIdx.x;
    const int b0  = blockIdx.x * 32;

    // ---- B build: thread (bks,bln) -> 3 LDS entries (d2l dropped: unused)
    {
        const int bks = tid >> 6;        // 0..7
        const int bln = tid & 63;
        const float* p = data + (size_t)(b0 + (bln & 31)) * NF
                              + bks * 16 + (bln >> 5) * 8;
        const float4 v0 = *(const float4*)(p);
        const float4 v1 = *(const float4*)(p + 4);
        const float dv[8] = {v0.x, v0.y, v0.z, v0.w, v1.x, v1.y, v1.z, v1.w};
        s16x8 e_d2, e_d, e_dl;
        #pragma unroll
        for (int j = 0; j < 8; ++j) {
            const float d  = dv[j];
            const unsigned short dh = f2bf(d);
            e_d2[j] = (short)f2bf(d * d);
            e_d [j] = (short)dh;
            e_dl[j] = (short)f2bf(d - bf2f(dh));
        }
        sB[0][bks][bln] = e_d2;
        sB[1][bks][bln] = e_d;
        sB[2][bks][bln] = e_dl;
    }

    // ---- Cr/W0 (coalesced; also pre-warms L2 with mu/sigma)
    {
        const int r   = tid >> 1;
        const int seg = tid & 1;
        const float* mrow = mu    + (size_t)r * NF + seg * 64;
        const float* srow = sigma + (size_t)r * NF + seg * 64;
        float cc = 0.f;
        #pragma unroll 4
        for (int q = 0; q < 64; q += 4) {
            const float4 s4 = *(const float4*)(srow + q);
            const float4 m4 = *(const float4*)(mrow + q);
            cc += (-0.5f / fmaxf(s4.x * s4.x, 1e-30f)) * m4.x * m4.x;
            cc += (-0.5f / fmaxf(s4.y * s4.y, 1e-30f)) * m4.y * m4.y;
            cc += (-0.5f / fmaxf(s4.z * s4.z, 1e-30f)) * m4.z * m4.z;
            cc += (-0.5f / fmaxf(s4.w * s4.w, 1e-30f)) * m4.w * m4.w;
        }
        cc += __shfl_xor(cc, 1);
        if (seg == 0) sCr[r] = cc;
        if (tid < NR) sW0[tid] = w3[(size_t)tid * (NF + 1)];
    }

    // ---- conversion lambda: thread t -> rule r=t>>1, f-half fh=t&1
    const int cr  = tid >> 1;
    const int cfh = tid & 1;
    const int ctile = cr >> 5;
    const int clane = cfh * 32 + (cr & 31);
    const float* cmu = mu    + (size_t)cr * NF;
    const float* csg = sigma + (size_t)cr * NF;
    const float* cw  = w3    + (size_t)cr * (NF + 1) + 1;

    auto conv = [&](int km, int buf) {
        const int f0 = km * 16 + cfh * 8;
        const float4 s40 = *(const float4*)(csg + f0);
        const float4 s41 = *(const float4*)(csg + f0 + 4);
        const float4 m40 = *(const float4*)(cmu + f0);
        const float4 m41 = *(const float4*)(cmu + f0 + 4);
        const float sv[8] = {s40.x, s40.y, s40.z, s40.w, s41.x, s41.y, s41.z, s41.w};
        const float mv[8] = {m40.x, m40.y, m40.z, m40.w, m41.x, m41.y, m41.z, m41.w};
        s16x8 vu2, vu1, vwh, vwl;
        #pragma unroll
        for (int j = 0; j < 8; ++j) {
            const float s  = sv[j];
            const float m  = mv[j];
            const float w  = cw[f0 + j];
            const float u2 = -0.5f / fmaxf(s * s, 1e-30f);
            vu2[j] = (short)f2bf(u2);
            vu1[j] = (short)f2bf(-2.0f * u2 * m);
            const unsigned short wh = f2bf(w);
            vwh[j] = (short)wh;
            vwl[j] = (short)f2bf(w - bf2f(wh));
        }
        sA[buf][0][ctile][clane] = vu2;
        sA[buf][1][ctile][clane] = vu1;
        sA[buf][2][ctile][clane] = vwh;
        sA[buf][3][ctile][clane] = vwl;
    };

    conv(0, 0);
    __syncthreads();

    const int wv   = tid >> 6;     // wave id == rule tile
    const int lane = tid & 63;
    const int col  = lane & 31;
    const int half = lane >> 5;

    f32x16 accS, accQ;
    #pragma unroll
    for (int e = 0; e < 16; ++e) { accS[e] = 0.f; accQ[e] = 0.f; }

    int buf = 0;
    #pragma unroll 1
    for (int km = 0; km < 8; ++km) {
        if (km < 7) conv(km + 1, buf ^ 1);   // overlaps MFMA below (other buf)

        const s16x8 a_u2 = sA[buf][0][wv][lane];
        const s16x8 a_u1 = sA[buf][1][wv][lane];
        const s16x8 a_wh = sA[buf][2][wv][lane];
        const s16x8 a_wl = sA[buf][3][wv][lane];
        const s16x8 b_d2 = sB[0][km][lane];
        const s16x8 b_dh = sB[1][km][lane];
        const s16x8 b_dl = sB[2][km][lane];

        accS = mfma_bf16(a_u2, b_d2, accS);   // u2_hi . d2_hi
        accS = mfma_bf16(a_u1, b_dh, accS);   // u1_hi . d_hi
        accQ = mfma_bf16(a_wh, b_dh, accQ);   // w_hi . d_hi
        accQ = mfma_bf16(a_wh, b_dl, accQ);   // w_hi . d_lo
        accQ = mfma_bf16(a_wl, b_dh, accQ);   // w_lo . d_hi

        __syncthreads();
        buf ^= 1;
    }

    float den_p = 0.f, num_p = 0.f;
    #pragma unroll
    for (int reg = 0; reg < 16; ++reg) {
        const int rloc = (reg & 3) + 8 * (reg >> 2) + 4 * half;
        const int rule = wv * 32 + rloc;
        const float S  = accS[reg] + sCr[rule];
        const float rv = __expf(fminf(S, 0.f)) - 28.0f;   // RULE_OFFSET (10^-18==-28)
        const float cq = accQ[reg] + sW0[rule];
        den_p += rv;
        num_p += rv * cq;
    }
    den_p += __shfl_xor(den_p, 32);
    num_p += __shfl_xor(num_p, 32);
    if (half == 0) { redD[wv][col] = den_p; redN[wv][col] = num_p; }
    __syncthreads();

    if (tid < 32) {
        float den = 0.f, num = 0.f;
        #pragma unroll
        for (int w = 0; w < 8; ++w) { den += redD[w][tid]; num += redN[w][tid]; }
        out[b0 + tid] = 1.0f / (1.0f + __expf(-(num / den)));
    }
}

// ---------------------------------------------------------------------------
// fallback (batch not divisible by 32): fused f32 (round-2, known-good).
// ---------------------------------------------------------------------------
#define TBF 8
__global__ __launch_bounds__(256) void fnn_fused(
    const float* __restrict__ data,
    const float* __restrict__ mu, const float* __restrict__ sigma,
    const float* __restrict__ w3,
    float* __restrict__ out)
{
    __shared__ float d_tile[TBF][NF];
    __shared__ float red[TBF][2][4];

    const int tid = threadIdx.x;
    const int b0  = blockIdx.x * TBF;
    {
        const float4* src = (const float4*)(data + (size_t)b0 * NF);
        ((float4*)(&d_tile[0][0]))[tid] = src[tid];
    }
    __syncthreads();

    const float* mu_r = mu    + (size_t)tid * NF;
    const float* sg_r = sigma + (size_t)tid * NF;
    const float* w_r  = w3    + (size_t)tid * (NF + 1);

    float S[TBF], Q[TBF];
    #pragma unroll
    for (int b = 0; b < TBF; ++b) { S[b] = 0.f; Q[b] = 0.f; }

    #pragma unroll 2
    for (int f = 0; f < NF; f += 4) {
        const float4 m4 = *(const float4*)(mu_r + f);
        const float4 s4 = *(const float4*)(sg_r + f);
        const float w0 = w_r[1 + f + 0], w1 = w_r[1 + f + 1];
        const float w2 = w_r[1 + f + 2], w3v = w_r[1 + f + 3];
        float4 c4;
        c4.x = -0.5f / fmaxf(s4.x * s4.x, 1e-30f);
        c4.y = -0.5f / fmaxf(s4.y * s4.y, 1e-30f);
        c4.z = -0.5f / fmaxf(s4.z * s4.z, 1e-30f);
        c4.w = -0.5f / fmaxf(s4.w * s4.w, 1e-30f);
        #pragma unroll
        for (int b = 0; b < TBF; ++b) {
            const float4 d4 = *(const float4*)(&d_tile[b][f]);
            float t;
            t = d4.x - m4.x; S[b] = fmaf(t * t, c4.x, S[b]); Q[b] = fmaf(d4.x, w0,  Q[b]);
            t = d4.y - m4.y; S[b] = fmaf(t * t, c4.y, S[b]); Q[b] = fmaf(d4.y, w1,  Q[b]);
            t = d4.z - m4.z; S[b] = fmaf(t * t, c4.z, S[b]); Q[b] = fmaf(d4.z, w2,  Q[b]);
            t = d4.w - m4.w; S[b] = fmaf(t * t, c4.w, S[b]); Q[b] = fmaf(d4.w, w3v, Q[b]);
        }
    }

    const float bias = w_r[0];
    #pragma unroll
    for (int b = 0; b < TBF; ++b) {
        float rule = __expf(S[b]) - 28.0f;
        float rc   = rule * (bias + Q[b]);
        #pragma unroll
        for (int off = 32; off > 0; off >>= 1) {
            rule += __shfl_down(rule, off);
            rc   += __shfl_down(rc,   off);
        }
        if ((tid & 63) == 0) {
            red[b][0][tid >> 6] = rule;
            red[b][1][tid >> 6] = rc;
        }
    }
    __syncthreads();
    if (tid < TBF) {
        const float den = red[tid][0][0] + red[tid][0][1] + red[tid][0][2] + red[tid][0][3];
        const float num = red[tid][1][0] + red[tid][1][1] + red[tid][1][2] + red[tid][1][3];
        out[b0 + tid] = 1.0f / (1.0f + __expf(-(num / den)));
    }
}

extern "C" void kernel_launch(void* const* d_in, const int* in_sizes, int n_in,
                              void* d_out, int out_size, void* d_ws, size_t ws_size,
                              hipStream_t stream) {
    const float* data  = (const float*)d_in[0];
    const float* mu    = (const float*)d_in[1];
    const float* sigma = (const float*)d_in[2];
    const float* w3    = (const float*)d_in[3];
    float* out = (float*)d_out;

    const int batch = in_sizes[0] / NF;   // 8192

    if ((batch % 32) == 0) {
        fnn_coop<<<batch / 32, 512, 0, stream>>>(data, mu, sigma, w3, out);
    } else {
        fnn_fused<<<batch / TBF, 256, 0, stream>>>(data, mu, sigma, w3, out);
    }
}

// Round 19
// 15.955 us; speedup vs baseline: 2.1031x; 1.6863x over previous
//
#include <hip/hip_runtime.h>
#include <math.h>

#define NR 256   // rules
#define NF 128   // features

typedef short  s16x8  __attribute__((ext_vector_type(8)));   // 8 bf16 bit patterns
typedef __bf16 bf16x8 __attribute__((ext_vector_type(8)));
typedef float  f32x16 __attribute__((ext_vector_type(16)));  // MFMA 32x32 acc

__device__ __forceinline__ unsigned short f2bf(float x) {
    unsigned int u = __float_as_uint(x);
    unsigned int r = (u + 0x7FFFu + ((u >> 16) & 1u)) >> 16;  // RNE
    return (unsigned short)r;
}
__device__ __forceinline__ float bf2f(unsigned short b) {
    return __uint_as_float(((unsigned int)b) << 16);
}
__device__ __forceinline__ bf16x8 as_bf(s16x8 v) {
    return __builtin_bit_cast(bf16x8, v);
}
__device__ __forceinline__ f32x16 mfma_bf16(s16x8 a, s16x8 b, f32x16 acc) {
    return __builtin_amdgcn_mfma_f32_32x32x16_bf16(as_bf(a), as_bf(b), acc, 0, 0, 0);
}

// ---------------------------------------------------------------------------
// prep2s (r19): prep2 minus the PL stream. r17/r18 validated on-harness that
// S needs only single-pass hi params (clamp min(S,0) absorbs conversion err;
// absmax stayed 0.00390625). Writes:
//   PH entries 0..7 = u2_hi, 8..15 = u1_hi ; WC entries 0..7 = w_hi, 8..15 = w_lo
//   (entry e = rt*16+ks2; rule = rt*32+(lane&31); f = (ks2&7)*16+(lane>>5)*8+j)
// Blocks 32..39: Cr[r] = sum_f u2*mu^2, W0[r] = w3[r][0].
// ---------------------------------------------------------------------------
__global__ __launch_bounds__(256) void prep2s_kernel(
    const float* __restrict__ mu, const float* __restrict__ sigma,
    const float* __restrict__ w3,
    unsigned short* __restrict__ PH, unsigned short* __restrict__ WC,
    float* __restrict__ Cr, float* __restrict__ W0)
{
    const int blk = blockIdx.x;
    if (blk < 32) {
        const int t    = blk * 256 + threadIdx.x;   // 0..8191
        const int e    = t >> 6;                     // entry 0..127
        const int lane = t & 63;
        const int rt   = e >> 4;
        const int ks2  = e & 15;
        const bool second = (ks2 >= 8);
        const int fb   = (ks2 & 7) * 16 + (lane >> 5) * 8;
        const int rule = rt * 32 + (lane & 31);

        const float* mrow = mu    + (size_t)rule * NF + fb;
        const float* srow = sigma + (size_t)rule * NF + fb;
        const float* wrow = w3    + (size_t)rule * (NF + 1) + 1 + fb;

        s16x8 vh, vw;
        #pragma unroll
        for (int j = 0; j < 8; ++j) {
            const float s  = srow[j];
            const float m  = mrow[j];
            const float w  = wrow[j];
            const float u2 = -0.5f / fmaxf(s * s, 1e-30f);
            const float val = second ? (-2.0f * u2 * m) : u2;
            vh[j] = (short)f2bf(val);
            const unsigned short wh = f2bf(w);
            vw[j] = (short)(second ? f2bf(w - bf2f(wh)) : wh);
        }
        ((s16x8*)PH)[t] = vh;   // t == e*64 + lane : fully coalesced 16B
        ((s16x8*)WC)[t] = vw;
    } else {
        const int rg   = blk - 32;                  // rule group of 32
        const int rl   = threadIdx.x >> 3;
        const int jj   = threadIdx.x & 7;
        const int rule = rg * 32 + rl;
        const float* mrow = mu    + (size_t)rule * NF + jj * 16;
        const float* srow = sigma + (size_t)rule * NF + jj * 16;
        float cc = 0.f;
        #pragma unroll
        for (int q = 0; q < 16; q += 4) {
            const float4 s4 = *(const float4*)(srow + q);
            const float4 m4 = *(const float4*)(mrow + q);
            cc += (-0.5f / fmaxf(s4.x * s4.x, 1e-30f)) * m4.x * m4.x;
            cc += (-0.5f / fmaxf(s4.y * s4.y, 1e-30f)) * m4.y * m4.y;
            cc += (-0.5f / fmaxf(s4.z * s4.z, 1e-30f)) * m4.z * m4.z;
            cc += (-0.5f / fmaxf(s4.w * s4.w, 1e-30f)) * m4.w * m4.w;
        }
        cc += __shfl_down(cc, 4);
        cc += __shfl_down(cc, 2);
        cc += __shfl_down(cc, 1);
        if (jj == 0) {
            Cr[rule] = cc;
            W0[rule] = w3[(size_t)rule * (NF + 1)];
        }
    }
}

// ---------------------------------------------------------------------------
// main v5 (r19): r14's deep X/Y pipeline, PL stream deleted (numerics
// validated r17/r18: absmax 0.00390625). 40 MFMA/wave (was 72), 2 A-streams
// (was 3), 24 KB B-LDS (was 32). Per km:
//   km<8 (entries 0..7):  accS += u2_hi.d2h ; accQ += w_hi.dh + w_hi.dl
//   km>=8 (entries 8..15): accS += u1_hi.dh ; accQ += w_lo.dh
// Epilogue: rule=exp(min(S+Cr,0))-28; 16-reg reduce; shfl_xor 32; LDS combine.
// C/D layout (HW-verified): col=lane&31, row=(reg&3)+8*(reg>>2)+4*(lane>>5)
// ---------------------------------------------------------------------------
__global__ __launch_bounds__(512) void fnn_mfma(
    const float* __restrict__ data,
    const unsigned short* __restrict__ PH, const unsigned short* __restrict__ WC,
    const float* __restrict__ Cr, const float* __restrict__ W0,
    float* __restrict__ out)
{
    __shared__ s16x8 sB0[8][64], sB1[8][64], sB2[8][64];  // d2h, dh, dl: 24 KB
    __shared__ float sCr[NR], sW0[NR];
    __shared__ float redD[8][32], redN[8][32];

    const int tid = threadIdx.x;
    if (tid < NR) sCr[tid] = Cr[tid];
    else          sW0[tid - NR] = W0[tid - NR];

    const int b0 = blockIdx.x * 32;

    // ---- cooperative B build: thread (bks,bln) -> 3 LDS entries
    {
        const int bks = tid >> 6;        // 0..7
        const int bln = tid & 63;
        const float* p = data + (size_t)(b0 + (bln & 31)) * NF
                              + bks * 16 + (bln >> 5) * 8;
        const float4 v0 = *(const float4*)(p);
        const float4 v1 = *(const float4*)(p + 4);
        const float dv[8] = {v0.x, v0.y, v0.z, v0.w, v1.x, v1.y, v1.z, v1.w};
        s16x8 e_d2, e_d, e_dl;
        #pragma unroll
        for (int j = 0; j < 8; ++j) {
            const float d  = dv[j];
            const unsigned short dh = f2bf(d);
            e_d2[j] = (short)f2bf(d * d);
            e_d [j] = (short)dh;
            e_dl[j] = (short)f2bf(d - bf2f(dh));
        }
        sB0[bks][bln] = e_d2;   // km<8  : d^2 hi
        sB1[bks][bln] = e_d;    // dh
        sB2[bks][bln] = e_dl;   // dl
    }
    __syncthreads();

    const int wv   = tid >> 6;     // wave id == rule tile
    const int lane = tid & 63;
    const int col  = lane & 31;
    const int half = lane >> 5;

    const s16x8* PHp = (const s16x8*)PH + (size_t)wv * 16 * 64 + lane;
    const s16x8* WCp = (const s16x8*)WC + (size_t)wv * 16 * 64 + lane;

    f32x16 accS, accQ;
    #pragma unroll
    for (int e = 0; e < 16; ++e) { accS[e] = 0.f; accQ[e] = 0.f; }

    // two rotating A-register groups (8 frags = 32 VGPR each)
    s16x8 X0h, X0w, X1h, X1w, X2h, X2w, X3h, X3w;
    s16x8 Y0h, Y0w, Y1h, Y1w, Y2h, Y2w, Y3h, Y3w;

#define LOADX(G) \
    X0h = PHp[((G)*4+0)*64]; X0w = WCp[((G)*4+0)*64]; \
    X1h = PHp[((G)*4+1)*64]; X1w = WCp[((G)*4+1)*64]; \
    X2h = PHp[((G)*4+2)*64]; X2w = WCp[((G)*4+2)*64]; \
    X3h = PHp[((G)*4+3)*64]; X3w = WCp[((G)*4+3)*64];
#define LOADY(G) \
    Y0h = PHp[((G)*4+0)*64]; Y0w = WCp[((G)*4+0)*64]; \
    Y1h = PHp[((G)*4+1)*64]; Y1w = WCp[((G)*4+1)*64]; \
    Y2h = PHp[((G)*4+2)*64]; Y2w = WCp[((G)*4+2)*64]; \
    Y3h = PHp[((G)*4+3)*64]; Y3w = WCp[((G)*4+3)*64];

// entries 0..7 (u2_hi / w_hi), B: d2h for S, dh+dl for Q
#define KS_LO(AH, AW, KM)                            \
    {                                                 \
        const s16x8 b2 = sB0[KM][lane];               \
        const s16x8 bh = sB1[KM][lane];               \
        const s16x8 bl = sB2[KM][lane];               \
        accS = mfma_bf16(AH, b2, accS);               \
        accQ = mfma_bf16(AW, bh, accQ);               \
        accQ = mfma_bf16(AW, bl, accQ);               \
    }
// entries 8..15 (u1_hi / w_lo), B: dh for both
#define KS_HI(AH, AW, KM)                            \
    {                                                 \
        const s16x8 bh = sB1[KM][lane];               \
        accS = mfma_bf16(AH, bh, accS);               \
        accQ = mfma_bf16(AW, bh, accQ);               \
    }

    LOADX(0)
    LOADY(1)
    KS_LO(X0h, X0w, 0)
    KS_LO(X1h, X1w, 1)
    KS_LO(X2h, X2w, 2)
    KS_LO(X3h, X3w, 3)
    __builtin_amdgcn_sched_barrier(0);
    LOADX(2)
    KS_LO(Y0h, Y0w, 4)
    KS_LO(Y1h, Y1w, 5)
    KS_LO(Y2h, Y2w, 6)
    KS_LO(Y3h, Y3w, 7)
    __builtin_amdgcn_sched_barrier(0);
    LOADY(3)
    KS_HI(X0h, X0w, 0)    // entry 8  <-> km 0
    KS_HI(X1h, X1w, 1)
    KS_HI(X2h, X2w, 2)
    KS_HI(X3h, X3w, 3)
    __builtin_amdgcn_sched_barrier(0);
    KS_HI(Y0h, Y0w, 4)    // entry 12 <-> km 4
    KS_HI(Y1h, Y1w, 5)
    KS_HI(Y2h, Y2w, 6)
    KS_HI(Y3h, Y3w, 7)

#undef LOADX
#undef LOADY
#undef KS_LO
#undef KS_HI

    float den_p = 0.f, num_p = 0.f;
    #pragma unroll
    for (int reg = 0; reg < 16; ++reg) {
        const int rloc = (reg & 3) + 8 * (reg >> 2) + 4 * half;
        const int rule = wv * 32 + rloc;
        const float S  = accS[reg] + sCr[rule];
        const float rv = __expf(fminf(S, 0.f)) - 28.0f;   // RULE_OFFSET (10^-18==-28)
        const float cq = accQ[reg] + sW0[rule];
        den_p += rv;
        num_p += rv * cq;
    }
    den_p += __shfl_xor(den_p, 32);
    num_p += __shfl_xor(num_p, 32);
    if (half == 0) { redD[wv][col] = den_p; redN[wv][col] = num_p; }
    __syncthreads();

    if (tid < 32) {
        float den = 0.f, num = 0.f;
        #pragma unroll
        for (int w = 0; w < 8; ++w) { den += redD[w][tid]; num += redN[w][tid]; }
        out[b0 + tid] = 1.0f / (1.0f + __expf(-(num / den)));
    }
}

// ---------------------------------------------------------------------------
// fallback (ws too small / batch mismatch): fused f32 (round-2, known-good).
// ---------------------------------------------------------------------------
#define TBF 8
__global__ __launch_bounds__(256) void fnn_fused(
    const float* __restrict__ data,
    const float* __restrict__ mu, const float* __restrict__ sigma,
    const float* __restrict__ w3,
    float* __restrict__ out)
{
    __shared__ float d_tile[TBF][NF];
    __shared__ float red[TBF][2][4];

    const int tid = threadIdx.x;
    const int b0  = blockIdx.x * TBF;
    {
        const float4* src = (const float4*)(data + (size_t)b0 * NF);
        ((float4*)(&d_tile[0][0]))[tid] = src[tid];
    }
    __syncthreads();

    const float* mu_r = mu    + (size_t)tid * NF;
    const float* sg_r = sigma + (size_t)tid * NF;
    const float* w_r  = w3    + (size_t)tid * (NF + 1);

    float S[TBF], Q[TBF];
    #pragma unroll
    for (int b = 0; b < TBF; ++b) { S[b] = 0.f; Q[b] = 0.f; }

    #pragma unroll 2
    for (int f = 0; f < NF; f += 4) {
        const float4 m4 = *(const float4*)(mu_r + f);
        const float4 s4 = *(const float4*)(sg_r + f);
        const float w0 = w_r[1 + f + 0], w1 = w_r[1 + f + 1];
        const float w2 = w_r[1 + f + 2], w3v = w_r[1 + f + 3];
        float4 c4;
        c4.x = -0.5f / fmaxf(s4.x * s4.x, 1e-30f);
        c4.y = -0.5f / fmaxf(s4.y * s4.y, 1e-30f);
        c4.z = -0.5f / fmaxf(s4.z * s4.z, 1e-30f);
        c4.w = -0.5f / fmaxf(s4.w * s4.w, 1e-30f);
        #pragma unroll
        for (int b = 0; b < TBF; ++b) {
            const float4 d4 = *(const float4*)(&d_tile[b][f]);
            float t;
            t = d4.x - m4.x; S[b] = fmaf(t * t, c4.x, S[b]); Q[b] = fmaf(d4.x, w0,  Q[b]);
            t = d4.y - m4.y; S[b] = fmaf(t * t, c4.y, S[b]); Q[b] = fmaf(d4.y, w1,  Q[b]);
            t = d4.z - m4.z; S[b] = fmaf(t * t, c4.z, S[b]); Q[b] = fmaf(d4.z, w2,  Q[b]);
            t = d4.w - m4.w; S[b] = fmaf(t * t, c4.w, S[b]); Q[b] = fmaf(d4.w, w3v, Q[b]);
        }
    }

    const float bias = w_r[0];
    #pragma unroll
    for (int b = 0; b < TBF; ++b) {
        float rule = __expf(S[b]) - 28.0f;
        float rc   = rule * (bias + Q[b]);
        #pragma unroll
        for (int off = 32; off > 0; off >>= 1) {
            rule += __shfl_down(rule, off);
            rc   += __shfl_down(rc,   off);
        }
        if ((tid & 63) == 0) {
            red[b][0][tid >> 6] = rule;
            red[b][1][tid >> 6] = rc;
        }
    }
    __syncthreads();
    if (tid < TBF) {
        const float den = red[tid][0][0] + red[tid][0][1] + red[tid][0][2] + red[tid][0][3];
        const float num = red[tid][1][0] + red[tid][1][1] + red[tid][1][2] + red[tid][1][3];
        out[b0 + tid] = 1.0f / (1.0f + __expf(-(num / den)));
    }
}

extern "C" void kernel_launch(void* const* d_in, const int* in_sizes, int n_in,
                              void* d_out, int out_size, void* d_ws, size_t ws_size,
                              hipStream_t stream) {
    const float* data  = (const float*)d_in[0];
    const float* mu    = (const float*)d_in[1];
    const float* sigma = (const float*)d_in[2];
    const float* w3    = (const float*)d_in[3];
    float* out = (float*)d_out;

    const int batch = in_sizes[0] / NF;   // 8192
    // PH + WC (2 x 64K bf16 = 2 x 128 KiB) + Cr + W0 = 264,192 B
    const size_t need = 2u * 65536u * sizeof(unsigned short) + 2u * NR * sizeof(float);

    if (ws_size >= need && (batch % 32) == 0) {
        unsigned short* PH = (unsigned short*)d_ws;
        unsigned short* WC = PH + 65536;
        float* Cr = (float*)(WC + 65536);
        float* W0 = Cr + NR;
        prep2s_kernel<<<40, 256, 0, stream>>>(mu, sigma, w3, PH, WC, Cr, W0);
        fnn_mfma<<<batch / 32, 512, 0, stream>>>(data, PH, WC, Cr, W0, out);
    } else {
        fnn_fused<<<batch / TBF, 256, 0, stream>>>(data, mu, sigma, w3, out);
    }
}

// Round 20
// 15.806 us; speedup vs baseline: 2.1230x; 1.0094x over previous
//
#include <hip/hip_runtime.h>
#include <math.h>

#define NR 256   // rules
#define NF 128   // features

typedef short  s16x8  __attribute__((ext_vector_type(8)));   // 8 bf16 bit patterns
typedef __bf16 bf16x8 __attribute__((ext_vector_type(8)));
typedef float  f32x16 __attribute__((ext_vector_type(16)));  // MFMA 32x32 acc

__device__ __forceinline__ unsigned short f2bf(float x) {
    unsigned int u = __float_as_uint(x);
    unsigned int r = (u + 0x7FFFu + ((u >> 16) & 1u)) >> 16;  // RNE
    return (unsigned short)r;
}
__device__ __forceinline__ float bf2f(unsigned short b) {
    return __uint_as_float(((unsigned int)b) << 16);
}
__device__ __forceinline__ bf16x8 as_bf(s16x8 v) {
    return __builtin_bit_cast(bf16x8, v);
}
__device__ __forceinline__ f32x16 mfma_bf16(s16x8 a, s16x8 b, f32x16 acc) {
    return __builtin_amdgcn_mfma_f32_32x32x16_bf16(as_bf(a), as_bf(b), acc, 0, 0, 0);
}

// ---------------------------------------------------------------------------
// prep2t (r20): prep2s minus the w_lo half of WC. Streams:
//   PH entries 0..15 : 0..7 = u2_hi, 8..15 = u1_hi          (128 KB)
//   WH entries 0..7  : w_hi                                  (64 KB)
// (entry e: rule = rt*32+(lane&31); f = (e&7)*16+(lane>>5)*8+j)
// Blocks 32..39: Cr[r] = sum_f u2*mu^2, W0[r] = w3[r][0].
// Error budget for dropping w_lo: |sum_f w_lo*d| ~ 5e-3..1e-2 on conq ->
// <=~5e-3 on sigmoid output; threshold 2e-2. (r17/r18 already validated the
// single-pass S + clamp.)
// ---------------------------------------------------------------------------
__global__ __launch_bounds__(256) void prep2t_kernel(
    const float* __restrict__ mu, const float* __restrict__ sigma,
    const float* __restrict__ w3,
    unsigned short* __restrict__ PH, unsigned short* __restrict__ WH,
    float* __restrict__ Cr, float* __restrict__ W0)
{
    const int blk = blockIdx.x;
    if (blk < 32) {
        const int t    = blk * 256 + threadIdx.x;   // 0..8191
        const int e    = t >> 6;                     // entry 0..127
        const int lane = t & 63;
        const int rt   = e >> 4;
        const int ks2  = e & 15;
        const bool second = (ks2 >= 8);
        const int fb   = (ks2 & 7) * 16 + (lane >> 5) * 8;
        const int rule = rt * 32 + (lane & 31);

        const float* mrow = mu    + (size_t)rule * NF + fb;
        const float* srow = sigma + (size_t)rule * NF + fb;
        const float* wrow = w3    + (size_t)rule * (NF + 1) + 1 + fb;

        s16x8 vh, vw;
        #pragma unroll
        for (int j = 0; j < 8; ++j) {
            const float s  = srow[j];
            const float m  = mrow[j];
            const float u2 = -0.5f / fmaxf(s * s, 1e-30f);
            const float val = second ? (-2.0f * u2 * m) : u2;
            vh[j] = (short)f2bf(val);
            vw[j] = (short)f2bf(wrow[j]);     // only used when !second
        }
        ((s16x8*)PH)[t] = vh;                 // coalesced 16B
        if (!second) {
            ((s16x8*)WH)[(size_t)(rt * 8 + ks2) * 64 + lane] = vw;
        }
    } else {
        const int rg   = blk - 32;                  // rule group of 32
        const int rl   = threadIdx.x >> 3;
        const int jj   = threadIdx.x & 7;
        const int rule = rg * 32 + rl;
        const float* mrow = mu    + (size_t)rule * NF + jj * 16;
        const float* srow = sigma + (size_t)rule * NF + jj * 16;
        float cc = 0.f;
        #pragma unroll
        for (int q = 0; q < 16; q += 4) {
            const float4 s4 = *(const float4*)(srow + q);
            const float4 m4 = *(const float4*)(mrow + q);
            cc += (-0.5f / fmaxf(s4.x * s4.x, 1e-30f)) * m4.x * m4.x;
            cc += (-0.5f / fmaxf(s4.y * s4.y, 1e-30f)) * m4.y * m4.y;
            cc += (-0.5f / fmaxf(s4.z * s4.z, 1e-30f)) * m4.z * m4.z;
            cc += (-0.5f / fmaxf(s4.w * s4.w, 1e-30f)) * m4.w * m4.w;
        }
        cc += __shfl_down(cc, 4);
        cc += __shfl_down(cc, 2);
        cc += __shfl_down(cc, 1);
        if (jj == 0) {
            Cr[rule] = cc;
            W0[rule] = w3[(size_t)rule * (NF + 1)];
        }
    }
}

// ---------------------------------------------------------------------------
// main v6 (r20): r19's X/Y pipeline, w_lo stream deleted. 32 MFMA/wave,
// 192 KB params/block (r19: 256 KB, r14: 384 KB). Per km:
//   km<8 (PH e0..7, WH e0..7): accS += u2_hi.d2h ; accQ += w_hi.dh + w_hi.dl
//   km>=8 (PH e8..15):          accS += u1_hi.dh
// Epilogue: rule=exp(min(S+Cr,0))-28; 16-reg reduce; shfl_xor 32; LDS combine.
// C/D layout (HW-verified): col=lane&31, row=(reg&3)+8*(reg>>2)+4*(lane>>5)
// ---------------------------------------------------------------------------
__global__ __launch_bounds__(512) void fnn_mfma(
    const float* __restrict__ data,
    const unsigned short* __restrict__ PH, const unsigned short* __restrict__ WH,
    const float* __restrict__ Cr, const float* __restrict__ W0,
    float* __restrict__ out)
{
    __shared__ s16x8 sB0[8][64], sB1[8][64], sB2[8][64];  // d2h, dh, dl: 24 KB
    __shared__ float sCr[NR], sW0[NR];
    __shared__ float redD[8][32], redN[8][32];

    const int tid = threadIdx.x;
    if (tid < NR) sCr[tid] = Cr[tid];
    else          sW0[tid - NR] = W0[tid - NR];

    const int b0 = blockIdx.x * 32;

    // ---- cooperative B build: thread (bks,bln) -> 3 LDS entries
    {
        const int bks = tid >> 6;        // 0..7
        const int bln = tid & 63;
        const float* p = data + (size_t)(b0 + (bln & 31)) * NF
                              + bks * 16 + (bln >> 5) * 8;
        const float4 v0 = *(const float4*)(p);
        const float4 v1 = *(const float4*)(p + 4);
        const float dv[8] = {v0.x, v0.y, v0.z, v0.w, v1.x, v1.y, v1.z, v1.w};
        s16x8 e_d2, e_d, e_dl;
        #pragma unroll
        for (int j = 0; j < 8; ++j) {
            const float d  = dv[j];
            const unsigned short dh = f2bf(d);
            e_d2[j] = (short)f2bf(d * d);
            e_d [j] = (short)dh;
            e_dl[j] = (short)f2bf(d - bf2f(dh));
        }
        sB0[bks][bln] = e_d2;   // km<8  : d^2 hi
        sB1[bks][bln] = e_d;    // dh
        sB2[bks][bln] = e_dl;   // dl
    }
    __syncthreads();

    const int wv   = tid >> 6;     // wave id == rule tile
    const int lane = tid & 63;
    const int col  = lane & 31;
    const int half = lane >> 5;

    const s16x8* PHp = (const s16x8*)PH + (size_t)wv * 16 * 64 + lane;
    const s16x8* WHp = (const s16x8*)WH + (size_t)wv * 8 * 64 + lane;

    f32x16 accS, accQ;
    #pragma unroll
    for (int e = 0; e < 16; ++e) { accS[e] = 0.f; accQ[e] = 0.f; }

    // rotating A-register groups
    s16x8 X0h, X0w, X1h, X1w, X2h, X2w, X3h, X3w;   // e0-3 / e8-11 reuse
    s16x8 Y0h, Y0w, Y1h, Y1w, Y2h, Y2w, Y3h, Y3w;   // e4-7 / e12-15 reuse

#define LOADX_LO \
    X0h = PHp[0*64]; X0w = WHp[0*64]; \
    X1h = PHp[1*64]; X1w = WHp[1*64]; \
    X2h = PHp[2*64]; X2w = WHp[2*64]; \
    X3h = PHp[3*64]; X3w = WHp[3*64];
#define LOADY_LO \
    Y0h = PHp[4*64]; Y0w = WHp[4*64]; \
    Y1h = PHp[5*64]; Y1w = WHp[5*64]; \
    Y2h = PHp[6*64]; Y2w = WHp[6*64]; \
    Y3h = PHp[7*64]; Y3w = WHp[7*64];
#define LOADX_HI \
    X0h = PHp[8*64];  X1h = PHp[9*64]; \
    X2h = PHp[10*64]; X3h = PHp[11*64];
#define LOADY_HI \
    Y0h = PHp[12*64]; Y1h = PHp[13*64]; \
    Y2h = PHp[14*64]; Y3h = PHp[15*64];

// entries 0..7 (u2_hi / w_hi): S += u2.d2h ; Q += wh.dh + wh.dl
#define KS_LO(AH, AW, KM)                            \
    {                                                 \
        const s16x8 b2 = sB0[KM][lane];               \
        const s16x8 bh = sB1[KM][lane];               \
        const s16x8 bl = sB2[KM][lane];               \
        accS = mfma_bf16(AH, b2, accS);               \
        accQ = mfma_bf16(AW, bh, accQ);               \
        accQ = mfma_bf16(AW, bl, accQ);               \
    }
// entries 8..15 (u1_hi): S += u1.dh
#define KS_HI(AH, KM)                                \
    {                                                 \
        const s16x8 bh = sB1[KM][lane];               \
        accS = mfma_bf16(AH, bh, accS);               \
    }

    LOADX_LO
    LOADY_LO
    KS_LO(X0h, X0w, 0)
    KS_LO(X1h, X1w, 1)
    KS_LO(X2h, X2w, 2)
    KS_LO(X3h, X3w, 3)
    __builtin_amdgcn_sched_barrier(0);
    LOADX_HI
    KS_LO(Y0h, Y0w, 4)
    KS_LO(Y1h, Y1w, 5)
    KS_LO(Y2h, Y2w, 6)
    KS_LO(Y3h, Y3w, 7)
    __builtin_amdgcn_sched_barrier(0);
    LOADY_HI
    KS_HI(X0h, 0)    // entry 8  <-> km 0
    KS_HI(X1h, 1)
    KS_HI(X2h, 2)
    KS_HI(X3h, 3)
    __builtin_amdgcn_sched_barrier(0);
    KS_HI(Y0h, 4)    // entry 12 <-> km 4
    KS_HI(Y1h, 5)
    KS_HI(Y2h, 6)
    KS_HI(Y3h, 7)

#undef LOADX_LO
#undef LOADY_LO
#undef LOADX_HI
#undef LOADY_HI
#undef KS_LO
#undef KS_HI

    float den_p = 0.f, num_p = 0.f;
    #pragma unroll
    for (int reg = 0; reg < 16; ++reg) {
        const int rloc = (reg & 3) + 8 * (reg >> 2) + 4 * half;
        const int rule = wv * 32 + rloc;
        const float S  = accS[reg] + sCr[rule];
        const float rv = __expf(fminf(S, 0.f)) - 28.0f;   // RULE_OFFSET (10^-18==-28)
        const float cq = accQ[reg] + sW0[rule];
        den_p += rv;
        num_p += rv * cq;
    }
    den_p += __shfl_xor(den_p, 32);
    num_p += __shfl_xor(num_p, 32);
    if (half == 0) { redD[wv][col] = den_p; redN[wv][col] = num_p; }
    __syncthreads();

    if (tid < 32) {
        float den = 0.f, num = 0.f;
        #pragma unroll
        for (int w = 0; w < 8; ++w) { den += redD[w][tid]; num += redN[w][tid]; }
        out[b0 + tid] = 1.0f / (1.0f + __expf(-(num / den)));
    }
}

// ---------------------------------------------------------------------------
// fallback (ws too small / batch mismatch): fused f32 (round-2, known-good).
// ---------------------------------------------------------------------------
#define TBF 8
__global__ __launch_bounds__(256) void fnn_fused(
    const float* __restrict__ data,
    const float* __restrict__ mu, const float* __restrict__ sigma,
    const float* __restrict__ w3,
    float* __restrict__ out)
{
    __shared__ float d_tile[TBF][NF];
    __shared__ float red[TBF][2][4];

    const int tid = threadIdx.x;
    const int b0  = blockIdx.x * TBF;
    {
        const float4* src = (const float4*)(data + (size_t)b0 * NF);
        ((float4*)(&d_tile[0][0]))[tid] = src[tid];
    }
    __syncthreads();

    const float* mu_r = mu    + (size_t)tid * NF;
    const float* sg_r = sigma + (size_t)tid * NF;
    const float* w_r  = w3    + (size_t)tid * (NF + 1);

    float S[TBF], Q[TBF];
    #pragma unroll
    for (int b = 0; b < TBF; ++b) { S[b] = 0.f; Q[b] = 0.f; }

    #pragma unroll 2
    for (int f = 0; f < NF; f += 4) {
        const float4 m4 = *(const float4*)(mu_r + f);
        const float4 s4 = *(const float4*)(sg_r + f);
        const float w0 = w_r[1 + f + 0], w1 = w_r[1 + f + 1];
        const float w2 = w_r[1 + f + 2], w3v = w_r[1 + f + 3];
        float4 c4;
        c4.x = -0.5f / fmaxf(s4.x * s4.x, 1e-30f);
        c4.y = -0.5f / fmaxf(s4.y * s4.y, 1e-30f);
        c4.z = -0.5f / fmaxf(s4.z * s4.z, 1e-30f);
        c4.w = -0.5f / fmaxf(s4.w * s4.w, 1e-30f);
        #pragma unroll
        for (int b = 0; b < TBF; ++b) {
            const float4 d4 = *(const float4*)(&d_tile[b][f]);
            float t;
            t = d4.x - m4.x; S[b] = fmaf(t * t, c4.x, S[b]); Q[b] = fmaf(d4.x, w0,  Q[b]);
            t = d4.y - m4.y; S[b] = fmaf(t * t, c4.y, S[b]); Q[b] = fmaf(d4.y, w1,  Q[b]);
            t = d4.z - m4.z; S[b] = fmaf(t * t, c4.z, S[b]); Q[b] = fmaf(d4.z, w2,  Q[b]);
            t = d4.w - m4.w; S[b] = fmaf(t * t, c4.w, S[b]); Q[b] = fmaf(d4.w, w3v, Q[b]);
        }
    }

    const float bias = w_r[0];
    #pragma unroll
    for (int b = 0; b < TBF; ++b) {
        float rule = __expf(S[b]) - 28.0f;
        float rc   = rule * (bias + Q[b]);
        #pragma unroll
        for (int off = 32; off > 0; off >>= 1) {
            rule += __shfl_down(rule, off);
            rc   += __shfl_down(rc,   off);
        }
        if ((tid & 63) == 0) {
            red[b][0][tid >> 6] = rule;
            red[b][1][tid >> 6] = rc;
        }
    }
    __syncthreads();
    if (tid < TBF) {
        const float den = red[tid][0][0] + red[tid][0][1] + red[tid][0][2] + red[tid][0][3];
        const float num = red[tid][1][0] + red[tid][1][1] + red[tid][1][2] + red[tid][1][3];
        out[b0 + tid] = 1.0f / (1.0f + __expf(-(num / den)));
    }
}

extern "C" void kernel_launch(void* const* d_in, const int* in_sizes, int n_in,
                              void* d_out, int out_size, void* d_ws, size_t ws_size,
                              hipStream_t stream) {
    const float* data  = (const float*)d_in[0];
    const float* mu    = (const float*)d_in[1];
    const float* sigma = (const float*)d_in[2];
    const float* w3    = (const float*)d_in[3];
    float* out = (float*)d_out;

    const int batch = in_sizes[0] / NF;   // 8192
    // PH (64K shorts) + WH (32K shorts) + Cr + W0 = 198,656 B
    const size_t need = (64u * 1024u + 32u * 1024u) * sizeof(unsigned short)
                      + 2u * NR * sizeof(float);

    if (ws_size >= need && (batch % 32) == 0) {
        unsigned short* PH = (unsigned short*)d_ws;
        unsigned short* WH = PH + 64 * 1024;
        float* Cr = (float*)(WH + 32 * 1024);
        float* W0 = Cr + NR;
        prep2t_kernel<<<40, 256, 0, stream>>>(mu, sigma, w3, PH, WH, Cr, W0);
        fnn_mfma<<<batch / 32, 512, 0, stream>>>(data, PH, WH, Cr, W0, out);
    } else {
        fnn_fused<<<batch / TBF, 256, 0, stream>>>(data, mu, sigma, w3, out);
    }
}